// Round 1
// 446.635 us; speedup vs baseline: 1.0367x; 1.0367x over previous
//
#include <hip/hip_runtime.h>

typedef _Float16 half8 __attribute__((ext_vector_type(8)));
typedef float floatx4 __attribute__((ext_vector_type(4)));

#define AS1 __attribute__((address_space(1)))
#define AS3 __attribute__((address_space(3)))

// ---------------------------------------------------------------------------
// W transpose + fp32->fp16: W [1024][1024] (k,n) -> Wt [1024][1024] (n,k)
// grid (16,16,3), block 256. 64x64 tiles through LDS.
// ---------------------------------------------------------------------------
__global__ __launch_bounds__(256) void wtrans_kernel(
    const float* __restrict__ W0, const float* __restrict__ W1,
    const float* __restrict__ W2, _Float16* __restrict__ Wt)
{
    __shared__ _Float16 t[64 * 72];
    const float* W = (blockIdx.z == 0) ? W0 : (blockIdx.z == 1) ? W1 : W2;
    _Float16* O = Wt + (long)blockIdx.z * 1048576;
    const int tid = threadIdx.x;
    const int kb = blockIdx.y * 64, nb = blockIdx.x * 64;
#pragma unroll
    for (int i = 0; i < 4; i++) {
        int r = (tid >> 4) + i * 16;
        int c = (tid & 15) * 4;
        floatx4 w = *(const floatx4*)&W[(long)(kb + r) * 1024 + nb + c];
#pragma unroll
        for (int j = 0; j < 4; j++) t[(c + j) * 72 + r] = (_Float16)w[j];
    }
    __syncthreads();
    const int c = tid >> 2, rch = (tid & 3) * 16;
    half8 v0 = *(const half8*)&t[c * 72 + rch];
    half8 v1 = *(const half8*)&t[c * 72 + rch + 8];
    _Float16* o = &O[(long)(nb + c) * 1024 + kb + rch];
    *(half8*)o = v0;
    *(half8*)(o + 8) = v1;
}

// ---------------------------------------------------------------------------
// fp32 -> fp16 cast, 8 elems/thread, grid-stride
// ---------------------------------------------------------------------------
__global__ __launch_bounds__(256) void f32_to_f16_kernel(
    const float* __restrict__ in, _Float16* __restrict__ out, int n)
{
    for (long i = ((long)blockIdx.x * 256 + threadIdx.x) * 8; i < n;
         i += (long)gridDim.x * 256 * 8) {
        floatx4 a = *(const floatx4*)&in[i];
        floatx4 b = *(const floatx4*)&in[i + 4];
        half8 h;
#pragma unroll
        for (int e = 0; e < 4; e++) { h[e] = (_Float16)a[e]; h[e + 4] = (_Float16)b[e]; }
        *(half8*)&out[i] = h;
    }
}

// ---------------------------------------------------------------------------
// Old m97-style 128x128 GEMM — kept ONLY for MODE 1 (V-proj with transposed
// fp16 output through LDS). MODE 0/2 paths superseded by gemm256_kernel.
// ---------------------------------------------------------------------------
template <int MODE>
__global__ __launch_bounds__(256) void gemm128_kernel(
    const _Float16* __restrict__ A, const _Float16* __restrict__ Bt,
    void* __restrict__ Cv, const float* __restrict__ bias,
    const float* __restrict__ bias2,
    int nx, int ny,
    int K, int lda, int ldb, int ldc,
    long aBatch, long bBatch, long cBatch, float scale)
{
    constexpr int SMEM_ELEMS = (MODE == 1) ? 17408 : 16384;
    __shared__ _Float16 smem[SMEM_ELEMS];
    _Float16* Ash = smem;
    _Float16* Bsh = smem + 8192;

    const int tid = threadIdx.x;
    const int wave = tid >> 6, lane = tid & 63;
    const int quad = lane >> 4, lr = lane & 15;
    const int wm = wave & 1, wn = wave >> 1;

    const int P = gridDim.x >> 3;
    const int g = (blockIdx.x & 7) * P + (blockIdx.x >> 3);
    const int pplane = nx * ny;
    const int z = g / pplane;
    const int rr = g - z * pplane;
    const int by = rr / nx;
    const int bx = rr - by * nx;
    const int m0 = by * 128, n0 = bx * 128;

    const _Float16* Ab = A + (long)z * aBatch;
    const _Float16* Bb = Bt + (long)z * bBatch;

    const int srow = tid >> 2;
    const int scol = (tid & 3) * 8;
    const long ag0 = (long)(m0 + srow) * lda + scol;
    const long bg0 = (long)(n0 + srow) * ldb + scol;
    const int sdst = tid * 8;

    floatx4 acc[4][4] = {};

    for (int k0 = 0; k0 < K; k0 += 64) {
#pragma unroll
        for (int s = 0; s < 2; s++) {
            const int kk = k0 + s * 32;
            const int so = s * 4096;
            __builtin_amdgcn_global_load_lds(
                (AS1 void*)(Ab + ag0 + kk), (AS3 void*)(Ash + so + sdst), 16, 0, 0);
            __builtin_amdgcn_global_load_lds(
                (AS1 void*)(Ab + ag0 + (long)64 * lda + kk), (AS3 void*)(Ash + so + sdst + 2048), 16, 0, 0);
            __builtin_amdgcn_global_load_lds(
                (AS1 void*)(Bb + bg0 + kk), (AS3 void*)(Bsh + so + sdst), 16, 0, 0);
            __builtin_amdgcn_global_load_lds(
                (AS1 void*)(Bb + bg0 + (long)64 * ldb + kk), (AS3 void*)(Bsh + so + sdst + 2048), 16, 0, 0);
        }
        __syncthreads();

#pragma unroll
        for (int s = 0; s < 2; s++) {
            const int so = s * 4096;
            half8 aF[4], bF[4];
#pragma unroll
            for (int i = 0; i < 4; i++) {
                aF[i] = *(const half8*)&Ash[so + (wm * 64 + i * 16 + lr) * 32 + quad * 8];
                bF[i] = *(const half8*)&Bsh[so + (wn * 64 + i * 16 + lr) * 32 + quad * 8];
            }
#pragma unroll
            for (int mi = 0; mi < 4; mi++)
#pragma unroll
                for (int ni = 0; ni < 4; ni++)
                    acc[mi][ni] = __builtin_amdgcn_mfma_f32_16x16x32_f16(
                        aF[mi], bF[ni], acc[mi][ni], 0, 0, 0);
        }
        __syncthreads();
    }

    if constexpr (MODE == 0) {
        _Float16* C = (_Float16*)Cv + (long)z * cBatch;
        const float* bz = (z == 0 || !bias2) ? bias : bias2;
#pragma unroll
        for (int ni = 0; ni < 4; ni++) {
            const int n = n0 + wn * 64 + ni * 16 + lr;
            const float bv_ = bz ? bz[n] : 0.0f;
#pragma unroll
            for (int mi = 0; mi < 4; mi++) {
                const int mb = m0 + wm * 64 + mi * 16 + quad * 4;
#pragma unroll
                for (int r = 0; r < 4; r++)
                    C[(long)(mb + r) * ldc + n] = (_Float16)((acc[mi][ni][r] + bv_) * scale);
            }
        }
    } else if constexpr (MODE == 1) {
        _Float16* ctile = smem;
#pragma unroll
        for (int ni = 0; ni < 4; ni++) {
            const int nl = wn * 64 + ni * 16 + lr;
            const float bv_ = bias ? bias[n0 + nl] : 0.0f;
#pragma unroll
            for (int mi = 0; mi < 4; mi++) {
                const int ml = wm * 64 + mi * 16 + quad * 4;
#pragma unroll
                for (int r = 0; r < 4; r++)
                    ctile[nl * 136 + ml + r] = (_Float16)((acc[mi][ni][r] + bv_) * scale);
            }
        }
        __syncthreads();
        _Float16* C = (_Float16*)Cv + (long)(m0 >> 11) * cBatch;
        const int t0 = m0 & 2047;
#pragma unroll
        for (int p = 0; p < 8; p++) {
            const int row = p * 16 + (tid >> 4);
            const int seg = (tid & 15) * 8;
            half8 v = *(const half8*)&ctile[row * 136 + seg];
            *(half8*)&C[(long)(n0 + row) * ldc + t0 + seg] = v;
        }
    } else {
        float* C = (float*)Cv + (long)z * cBatch;
#pragma unroll
        for (int ni = 0; ni < 4; ni++) {
            const int n = n0 + wn * 64 + ni * 16 + lr;
#pragma unroll
            for (int mi = 0; mi < 4; mi++) {
                const int mb = m0 + wm * 64 + mi * 16 + quad * 4;
#pragma unroll
                for (int r = 0; r < 4; r++)
                    C[(long)(mb + r) * ldc + n] = acc[mi][ni][r] * scale;
            }
        }
    }
}

// ---------------------------------------------------------------------------
// 256x256 8-phase GEMM (T2+T3+T4+T5 stack, plain HIP).
//   C[m][n] = sum_k A[m][k] * Bt[n][k]   (both fp16 row-major)
// 512 threads = 8 waves (2M x 4N), per-wave 128x64 output, BK=64.
// LDS 128 KiB: A[2 dbuf][2 half][128 x 64] | B same.
//   A half h = rows {h*64..h*64+63} U {128+h*64..}; local row = (r&63)|((r>>7)<<6)
//   B half h = cols with bit5==h;     local row = (c&31)|((c>>6)<<5)
// XOR swizzle (rule 21, both-sides): 16B chunk c of local row s holds global
// chunk c^(s&7); staged via pre-swizzled GLOBAL source + linear gload_lds dest;
// reads XOR the chunk back -> residual conflict 2-way (free, m136).
// Per K-tile: 4 phases {ds_read | stage 1 half-tile | s_barrier | MFMA x16}.
// vmcnt(4) ONCE per tile boundary: the 2 half-tiles of t+2 stay in flight.
// Death schedule: stage into buf d only regions last read >=2 barriers ago.
// MODE 0: fp16 out row-major, (+bias per z)*scale.  MODE 2: fp32 out.
// ---------------------------------------------------------------------------
#define STAGE_A(d, h, kt) do { \
    __builtin_amdgcn_global_load_lds((AS1 void*)(Ap + (long)((h) * 64) * lda + (long)(kt) * 64), \
        (AS3 void*)(Ash + (d) * 16384 + (h) * 8192 + sdst), 16, 0, 0); \
    __builtin_amdgcn_global_load_lds((AS1 void*)(Ap + (long)((h) * 64 + 128) * lda + (long)(kt) * 64), \
        (AS3 void*)(Ash + (d) * 16384 + (h) * 8192 + 4096 + sdst), 16, 0, 0); \
} while (0)

#define STAGE_B(d, h, kt) do { \
    __builtin_amdgcn_global_load_lds((AS1 void*)(Bp0 + (long)((h) * 32) * ldb + (long)(kt) * 64), \
        (AS3 void*)(Bsh + (d) * 16384 + (h) * 8192 + sdst), 16, 0, 0); \
    __builtin_amdgcn_global_load_lds((AS1 void*)(Bp1 + (long)((h) * 32) * ldb + (long)(kt) * 64), \
        (AS3 void*)(Bsh + (d) * 16384 + (h) * 8192 + 4096 + sdst), 16, 0, 0); \
} while (0)

#define LDA_FRAGS(d, mh) do { \
    _Pragma("unroll") for (int mi_ = 0; mi_ < 4; mi_++) { \
        const _Float16* p_ = &Ash[(d) * 16384 + (mh) * 8192 + (arow + mi_ * 16) * 64]; \
        aF[mi_][0] = *(const half8*)&p_[kq0]; \
        aF[mi_][1] = *(const half8*)&p_[kq1]; \
    } \
} while (0)

#define LDB_FRAGS(d, nh) do { \
    _Pragma("unroll") for (int ni_ = 0; ni_ < 2; ni_++) { \
        const _Float16* p_ = &Bsh[(d) * 16384 + (nh) * 8192 + (brow + ni_ * 16) * 64]; \
        bF[nh][ni_][0] = *(const half8*)&p_[kq0]; \
        bF[nh][ni_][1] = *(const half8*)&p_[kq1]; \
    } \
} while (0)

#define MFMA16(mh, nh) do { \
    __builtin_amdgcn_s_setprio(1); \
    _Pragma("unroll") for (int mi_ = 0; mi_ < 4; mi_++) \
    _Pragma("unroll") for (int ni_ = 0; ni_ < 2; ni_++) { \
        acc[(mh) * 4 + mi_][(nh) * 2 + ni_] = __builtin_amdgcn_mfma_f32_16x16x32_f16( \
            aF[mi_][0], bF[nh][ni_][0], acc[(mh) * 4 + mi_][(nh) * 2 + ni_], 0, 0, 0); \
        acc[(mh) * 4 + mi_][(nh) * 2 + ni_] = __builtin_amdgcn_mfma_f32_16x16x32_f16( \
            aF[mi_][1], bF[nh][ni_][1], acc[(mh) * 4 + mi_][(nh) * 2 + ni_], 0, 0, 0); \
    } \
    __builtin_amdgcn_s_setprio(0); \
} while (0)

#define PHASE_SYNC() do { \
    __builtin_amdgcn_s_barrier(); \
    __builtin_amdgcn_sched_barrier(0); \
} while (0)

template <int MODE>
__global__ __launch_bounds__(512, 2) void gemm256_kernel(
    const _Float16* __restrict__ A, const _Float16* __restrict__ Bt,
    void* __restrict__ Cv, const float* __restrict__ bias,
    const float* __restrict__ bias2,
    int nx, int ny, int K, int lda, int ldb, int ldc,
    long aBatch, long bBatch, long cBatch, float scale)
{
    __shared__ _Float16 smem[65536];   // 128 KiB
    _Float16* Ash = smem;
    _Float16* Bsh = smem + 32768;

    const int tid = threadIdx.x;
    const int wave = tid >> 6, lane = tid & 63;
    const int quad = lane >> 4, lr = lane & 15;
    const int wm = wave >> 2, wn = wave & 3;

    // XCD-aware swizzle (grid % 8 == 0 for all our launches)
    const int P = gridDim.x >> 3;
    const int g = (blockIdx.x & 7) * P + (blockIdx.x >> 3);
    const int pplane = nx * ny;
    const int z = g / pplane;
    const int rr = g - z * pplane;
    const int by = rr / nx;
    const int bx = rr - by * nx;
    const int m0 = by * 256, n0 = bx * 256;

    const _Float16* Ab = A + (long)z * aBatch;
    const _Float16* Bb = Bt + (long)z * bBatch;

    // ---- staging geometry: thread -> (local row sr, swizzled 16B chunk) ----
    const int sr0 = tid >> 3;                   // 0..63 (load 0); load 1 adds 64
    const int sc0 = (tid & 7) ^ (sr0 & 7);      // pre-swizzled global chunk
    const _Float16* Ap = Ab + (long)(m0 + sr0) * lda + sc0 * 8;
    const int bc0 = (sr0 & 31) + ((sr0 >> 5) << 6);          // B col, load 0, h=0
    const int bc1 = (sr0 & 31) + (((sr0 >> 5) + 2) << 6);    // B col, load 1, h=0
    const _Float16* Bp0 = Bb + (long)(n0 + bc0) * ldb + sc0 * 8;
    const _Float16* Bp1 = Bb + (long)(n0 + bc1) * ldb + sc0 * 8;
    const int sdst = tid * 8;                   // LDS elem offset (linear dest)

    // ---- fragment-read geometry (k-chunk XOR'd back) ----
    const int kq0 = (quad * 8) ^ ((lr & 7) << 3);
    const int kq1 = (32 + quad * 8) ^ ((lr & 7) << 3);
    const int arow = wm * 64 + lr;              // + mi*16 = A local row
    const int brow = wn * 32 + lr;              // + ni*16 = B local row

    half8 aF[4][2];        // [mi][ks], reloaded per mh
    half8 bF[2][2][2];     // [nh][ni][ks], held across the whole tile
    floatx4 acc[8][4] = {};
    const int NT = K >> 6;

    // ---- prologue: tile0 {A0,A1,B0,B1} + tile1 {A0,B0} = 12 loads/thread ----
    STAGE_A(0, 0, 0); STAGE_A(0, 1, 0); STAGE_B(0, 0, 0); STAGE_B(0, 1, 0);
    if (NT > 1) { STAGE_A(1, 0, 1); STAGE_B(1, 0, 1); }
    asm volatile("s_waitcnt vmcnt(4)" ::: "memory");   // tile0's 8 loads landed
    __builtin_amdgcn_s_barrier();
    __builtin_amdgcn_sched_barrier(0);

    for (int t = 0; t < NT; t++) {
        const int d = t & 1, dn = d ^ 1;
        // phase 0: quadrant (mh=0, nh=0); stage (t+1).A1 -> other buf
        LDA_FRAGS(d, 0); LDB_FRAGS(d, 0);
        if (t + 1 < NT) STAGE_A(dn, 1, t + 1);
        PHASE_SYNC();
        MFMA16(0, 0);
        PHASE_SYNC();
        // phase 1: (0,1); stage (t+1).B1 -> other buf
        LDB_FRAGS(d, 1);
        if (t + 1 < NT) STAGE_B(dn, 1, t + 1);
        PHASE_SYNC();
        MFMA16(0, 1);
        PHASE_SYNC();
        // phase 2: (1,0); stage (t+2).A0 -> THIS buf (A-h0 dead since p0)
        LDA_FRAGS(d, 1);
        if (t + 2 < NT) STAGE_A(d, 0, t + 2);
        PHASE_SYNC();
        MFMA16(1, 0);
        PHASE_SYNC();
        // phase 3: (1,1); stage (t+2).B0 -> THIS buf (B-h0 dead since p0)
        if (t + 2 < NT) STAGE_B(d, 0, t + 2);
        PHASE_SYNC();
        MFMA16(1, 1);
        PHASE_SYNC();
        // tile boundary: all 4 halves of t+1 resident; t+2's {A0,B0} in flight
        if (t + 1 < NT) {
            if (t + 2 < NT) asm volatile("s_waitcnt vmcnt(4)" ::: "memory");
            else            asm volatile("s_waitcnt vmcnt(0)" ::: "memory");
            __builtin_amdgcn_s_barrier();
            __builtin_amdgcn_sched_barrier(0);
        }
    }

    // ---- epilogue ----  C/D frag: m = quad*4 + r, n = lane&15
    if constexpr (MODE == 0) {
        _Float16* C = (_Float16*)Cv + (long)z * cBatch;
        const float* bz = (z == 0 || !bias2) ? bias : bias2;
#pragma unroll
        for (int ni = 0; ni < 4; ni++) {
            const int n = n0 + wn * 64 + ni * 16 + lr;
            const float bv_ = bz ? bz[n] : 0.0f;
#pragma unroll
            for (int mi = 0; mi < 8; mi++) {
                const int mb = m0 + wm * 128 + mi * 16 + quad * 4;
#pragma unroll
                for (int r = 0; r < 4; r++)
                    C[(long)(mb + r) * ldc + n] = (_Float16)((acc[mi][ni][r] + bv_) * scale);
            }
        }
    } else {
        float* C = (float*)Cv + (long)z * cBatch;
#pragma unroll
        for (int ni = 0; ni < 4; ni++) {
            const int n = n0 + wn * 64 + ni * 16 + lr;
#pragma unroll
            for (int mi = 0; mi < 8; mi++) {
                const int mb = m0 + wm * 128 + mi * 16 + quad * 4;
#pragma unroll
                for (int r = 0; r < 4; r++)
                    C[(long)(mb + r) * ldc + n] = acc[mi][ni][r] * scale;
            }
        }
    }
}

#undef STAGE_A
#undef STAGE_B
#undef LDA_FRAGS
#undef LDB_FRAGS
#undef MFMA16
#undef PHASE_SYNC

// ---------------------------------------------------------------------------
// row softmax, in place, fp16. One wave per row of 2048. block=256 -> 4 rows.
// ---------------------------------------------------------------------------
__global__ __launch_bounds__(256) void softmax_kernel(_Float16* __restrict__ buf)
{
    const int lane = threadIdx.x & 63;
    const long row = (long)blockIdx.x * 4 + (threadIdx.x >> 6);
    _Float16* p = buf + row * 2048;

    float f[32];
#pragma unroll
    for (int j = 0; j < 4; j++) {
        half8 v = *(const half8*)&p[lane * 8 + j * 512];
#pragma unroll
        for (int e = 0; e < 8; e++) f[j * 8 + e] = (float)v[e];
    }
    float m = -1e30f;
#pragma unroll
    for (int i = 0; i < 32; i++) m = fmaxf(m, f[i]);
#pragma unroll
    for (int off = 32; off; off >>= 1) m = fmaxf(m, __shfl_xor(m, off, 64));
    float s = 0.0f;
#pragma unroll
    for (int i = 0; i < 32; i++) { f[i] = __expf(f[i] - m); s += f[i]; }
#pragma unroll
    for (int off = 32; off; off >>= 1) s += __shfl_xor(s, off, 64);
    const float inv = 1.0f / s;
#pragma unroll
    for (int j = 0; j < 4; j++) {
        half8 v;
#pragma unroll
        for (int e = 0; e < 8; e++) v[e] = (_Float16)(f[j * 8 + e] * inv);
        *(half8*)&p[lane * 8 + j * 512] = v;
    }
}

// ---------------------------------------------------------------------------
// B=8, S=2048, D=1024.  Workspace layout (bytes):
//   Q   fp16 [16384][1024]            @ 0          (33,554,432)
//   Kb  fp16 [16384][1024]            @ 33,554,432 (33,554,432)   (contig w/ Q)
//   Vt  fp16 [8][1024][2048]          @ 67,108,864 (33,554,432)
//   Sc  fp16 [8][2048][2048]          @ 100,663,296 (67,108,864)  (xb aliased)
//   Wt  fp16 [3][1024][1024]          @ 167,772,160 (6,291,456)
// total 174,063,616
// ---------------------------------------------------------------------------
extern "C" void kernel_launch(void* const* d_in, const int* in_sizes, int n_in,
                              void* d_out, int out_size, void* d_ws, size_t ws_size,
                              hipStream_t stream)
{
    const float* x  = (const float*)d_in[0];
    const float* Wq = (const float*)d_in[1];
    const float* bq = (const float*)d_in[2];
    const float* Wk = (const float*)d_in[3];
    const float* bk = (const float*)d_in[4];
    const float* Wv = (const float*)d_in[5];
    const float* bv = (const float*)d_in[6];

    if (ws_size < 174063616u) return;  // cannot run

    char* ws = (char*)d_ws;
    _Float16* Q  = (_Float16*)(ws + 0);
    _Float16* Vt = (_Float16*)(ws + 67108864);
    _Float16* Sc = (_Float16*)(ws + 100663296);
    _Float16* Wt = (_Float16*)(ws + 167772160);
    _Float16* xb = Sc;  // aliased: xb dead before Sc is written
    _Float16* Kb = Q + 16777216;
    float* out = (float*)d_out;

    wtrans_kernel<<<dim3(16, 16, 3), 256, 0, stream>>>(Wq, Wk, Wv, Wt);
    f32_to_f16_kernel<<<2048, 256, 0, stream>>>(x, xb, 16777216);

    // Q and K projections fused via z: M=16384, N=1024, K=1024 -> 512 blocks
    gemm256_kernel<0><<<512, 512, 0, stream>>>(
        xb, Wt, Q, bq, bk, 4, 64, 1024, 1024, 1024, 1024,
        0, 1048576, 16777216, 1.0f);
    // V projection -> Vt [b][d][t] (old 128^2 MODE-1 kernel), 1024 blocks
    gemm128_kernel<1><<<1024, 256, 0, stream>>>(
        xb, Wt + 2097152, Vt, bv, nullptr, 8, 128, 1024, 1024, 1024, 2048,
        0, 0, 2097152, 1.0f);

    // scores = Q K^T / 32 : per-batch M=N=2048, K=1024 -> 512 blocks
    gemm256_kernel<0><<<512, 512, 0, stream>>>(
        Q, Kb, Sc, nullptr, nullptr, 8, 8, 1024, 1024, 1024, 2048,
        2097152, 2097152, 4194304, 0.03125f);

    softmax_kernel<<<4096, 256, 0, stream>>>(Sc);

    // out = P V : per-batch M=2048, N=1024, K=2048 -> 256 blocks
    gemm256_kernel<2><<<256, 512, 0, stream>>>(
        Sc, Vt, out, nullptr, nullptr, 4, 8, 2048, 2048, 2048, 1024,
        4194304, 2097152, 2097152, 1.0f);
}

// Round 3
// 445.333 us; speedup vs baseline: 1.0397x; 1.0029x over previous
//
#include <hip/hip_runtime.h>

typedef _Float16 half8 __attribute__((ext_vector_type(8)));
typedef float floatx4 __attribute__((ext_vector_type(4)));

#define AS1 __attribute__((address_space(1)))
#define AS3 __attribute__((address_space(3)))

// ---------------------------------------------------------------------------
// W transpose + fp32->fp16: W [1024][1024] (k,n) -> Wt [1024][1024] (n,k)
// grid (16,16,3), block 256. 64x64 tiles through LDS.
// ---------------------------------------------------------------------------
__global__ __launch_bounds__(256) void wtrans_kernel(
    const float* __restrict__ W0, const float* __restrict__ W1,
    const float* __restrict__ W2, _Float16* __restrict__ Wt)
{
    __shared__ _Float16 t[64 * 72];
    const float* W = (blockIdx.z == 0) ? W0 : (blockIdx.z == 1) ? W1 : W2;
    _Float16* O = Wt + (long)blockIdx.z * 1048576;
    const int tid = threadIdx.x;
    const int kb = blockIdx.y * 64, nb = blockIdx.x * 64;
#pragma unroll
    for (int i = 0; i < 4; i++) {
        int r = (tid >> 4) + i * 16;
        int c = (tid & 15) * 4;
        floatx4 w = *(const floatx4*)&W[(long)(kb + r) * 1024 + nb + c];
#pragma unroll
        for (int j = 0; j < 4; j++) t[(c + j) * 72 + r] = (_Float16)w[j];
    }
    __syncthreads();
    const int c = tid >> 2, rch = (tid & 3) * 16;
    half8 v0 = *(const half8*)&t[c * 72 + rch];
    half8 v1 = *(const half8*)&t[c * 72 + rch + 8];
    _Float16* o = &O[(long)(nb + c) * 1024 + kb + rch];
    *(half8*)o = v0;
    *(half8*)(o + 8) = v1;
}

// ---------------------------------------------------------------------------
// fp32 -> fp16 cast, 8 elems/thread, grid-stride
// ---------------------------------------------------------------------------
__global__ __launch_bounds__(256) void f32_to_f16_kernel(
    const float* __restrict__ in, _Float16* __restrict__ out, int n)
{
    for (long i = ((long)blockIdx.x * 256 + threadIdx.x) * 8; i < n;
         i += (long)gridDim.x * 256 * 8) {
        floatx4 a = *(const floatx4*)&in[i];
        floatx4 b = *(const floatx4*)&in[i + 4];
        half8 h;
#pragma unroll
        for (int e = 0; e < 4; e++) { h[e] = (_Float16)a[e]; h[e + 4] = (_Float16)b[e]; }
        *(half8*)&out[i] = h;
    }
}

// ---------------------------------------------------------------------------
// Old m97-style 128x128 GEMM — kept ONLY for MODE 1 (V-proj with transposed
// fp16 output through LDS).
// ---------------------------------------------------------------------------
template <int MODE>
__global__ __launch_bounds__(256) void gemm128_kernel(
    const _Float16* __restrict__ A, const _Float16* __restrict__ Bt,
    void* __restrict__ Cv, const float* __restrict__ bias,
    const float* __restrict__ bias2,
    int nx, int ny,
    int K, int lda, int ldb, int ldc,
    long aBatch, long bBatch, long cBatch, float scale)
{
    constexpr int SMEM_ELEMS = (MODE == 1) ? 17408 : 16384;
    __shared__ _Float16 smem[SMEM_ELEMS];
    _Float16* Ash = smem;
    _Float16* Bsh = smem + 8192;

    const int tid = threadIdx.x;
    const int wave = tid >> 6, lane = tid & 63;
    const int quad = lane >> 4, lr = lane & 15;
    const int wm = wave & 1, wn = wave >> 1;

    const int P = gridDim.x >> 3;
    const int g = (blockIdx.x & 7) * P + (blockIdx.x >> 3);
    const int pplane = nx * ny;
    const int z = g / pplane;
    const int rr = g - z * pplane;
    const int by = rr / nx;
    const int bx = rr - by * nx;
    const int m0 = by * 128, n0 = bx * 128;

    const _Float16* Ab = A + (long)z * aBatch;
    const _Float16* Bb = Bt + (long)z * bBatch;

    const int srow = tid >> 2;
    const int scol = (tid & 3) * 8;
    const long ag0 = (long)(m0 + srow) * lda + scol;
    const long bg0 = (long)(n0 + srow) * ldb + scol;
    const int sdst = tid * 8;

    floatx4 acc[4][4] = {};

    for (int k0 = 0; k0 < K; k0 += 64) {
#pragma unroll
        for (int s = 0; s < 2; s++) {
            const int kk = k0 + s * 32;
            const int so = s * 4096;
            __builtin_amdgcn_global_load_lds(
                (AS1 void*)(Ab + ag0 + kk), (AS3 void*)(Ash + so + sdst), 16, 0, 0);
            __builtin_amdgcn_global_load_lds(
                (AS1 void*)(Ab + ag0 + (long)64 * lda + kk), (AS3 void*)(Ash + so + sdst + 2048), 16, 0, 0);
            __builtin_amdgcn_global_load_lds(
                (AS1 void*)(Bb + bg0 + kk), (AS3 void*)(Bsh + so + sdst), 16, 0, 0);
            __builtin_amdgcn_global_load_lds(
                (AS1 void*)(Bb + bg0 + (long)64 * ldb + kk), (AS3 void*)(Bsh + so + sdst + 2048), 16, 0, 0);
        }
        __syncthreads();

#pragma unroll
        for (int s = 0; s < 2; s++) {
            const int so = s * 4096;
            half8 aF[4], bF[4];
#pragma unroll
            for (int i = 0; i < 4; i++) {
                aF[i] = *(const half8*)&Ash[so + (wm * 64 + i * 16 + lr) * 32 + quad * 8];
                bF[i] = *(const half8*)&Bsh[so + (wn * 64 + i * 16 + lr) * 32 + quad * 8];
            }
#pragma unroll
            for (int mi = 0; mi < 4; mi++)
#pragma unroll
                for (int ni = 0; ni < 4; ni++)
                    acc[mi][ni] = __builtin_amdgcn_mfma_f32_16x16x32_f16(
                        aF[mi], bF[ni], acc[mi][ni], 0, 0, 0);
        }
        __syncthreads();
    }

    if constexpr (MODE == 0) {
        _Float16* C = (_Float16*)Cv + (long)z * cBatch;
        const float* bz = (z == 0 || !bias2) ? bias : bias2;
#pragma unroll
        for (int ni = 0; ni < 4; ni++) {
            const int n = n0 + wn * 64 + ni * 16 + lr;
            const float bv_ = bz ? bz[n] : 0.0f;
#pragma unroll
            for (int mi = 0; mi < 4; mi++) {
                const int mb = m0 + wm * 64 + mi * 16 + quad * 4;
#pragma unroll
                for (int r = 0; r < 4; r++)
                    C[(long)(mb + r) * ldc + n] = (_Float16)((acc[mi][ni][r] + bv_) * scale);
            }
        }
    } else if constexpr (MODE == 1) {
        _Float16* ctile = smem;
#pragma unroll
        for (int ni = 0; ni < 4; ni++) {
            const int nl = wn * 64 + ni * 16 + lr;
            const float bv_ = bias ? bias[n0 + nl] : 0.0f;
#pragma unroll
            for (int mi = 0; mi < 4; mi++) {
                const int ml = wm * 64 + mi * 16 + quad * 4;
#pragma unroll
                for (int r = 0; r < 4; r++)
                    ctile[nl * 136 + ml + r] = (_Float16)((acc[mi][ni][r] + bv_) * scale);
            }
        }
        __syncthreads();
        _Float16* C = (_Float16*)Cv + (long)(m0 >> 11) * cBatch;
        const int t0 = m0 & 2047;
#pragma unroll
        for (int p = 0; p < 8; p++) {
            const int row = p * 16 + (tid >> 4);
            const int seg = (tid & 15) * 8;
            half8 v = *(const half8*)&ctile[row * 136 + seg];
            *(half8*)&C[(long)(n0 + row) * ldc + t0 + seg] = v;
        }
    } else {
        float* C = (float*)Cv + (long)z * cBatch;
#pragma unroll
        for (int ni = 0; ni < 4; ni++) {
            const int n = n0 + wn * 64 + ni * 16 + lr;
#pragma unroll
            for (int mi = 0; mi < 4; mi++) {
                const int mb = m0 + wm * 64 + mi * 16 + quad * 4;
#pragma unroll
                for (int r = 0; r < 4; r++)
                    C[(long)(mb + r) * ldc + n] = acc[mi][ni][r] * scale;
            }
        }
    }
}

// ---------------------------------------------------------------------------
// 256x256 8-phase GEMM (T2+T3+T4+T5 stack, plain HIP).
//   C[m][n] = sum_k A[m][k] * Bt[n][k]   (both fp16 row-major)
// 512 threads = 8 waves (2M x 4N), per-wave 128x64 output, BK=64.
// LDS 128 KiB: A[2 dbuf][2 half][128 x 64] | B same.
// XOR swizzle (both-sides): 16B chunk c of local row s holds global chunk
// c^(s&7); staged via pre-swizzled GLOBAL source + linear gload_lds dest;
// reads XOR the chunk back -> 0 bank conflicts (verified round 1).
// Per K-tile: 4 phases {ds_read | stage half-tile | s_barrier | MFMA x16 |
// s_barrier}; counted vmcnt(4) folded into phase 3's closing barrier (never
// 0 in steady state).
// Scheduling policy: NO sched_barrier(0) (m141: full order-pinning = -42%).
// Each s_barrier instead carries an EMPTY asm memory clobber — zero emitted
// instructions, but forbids the compiler from hoisting/sinking LDS or global
// accesses across the barrier (raw s_barrier builtin is not an IR-level
// memory fence). Machine scheduler stays free to interleave VALU/addr-gen
// with MFMA inside each phase.
// Death schedule: stage into buf d only regions last read >=2 barriers ago.
// MODE 0: fp16 out row-major, (+bias per z)*scale.  MODE 2: fp32 out.
// ---------------------------------------------------------------------------
#define STAGE_A(d, h, kt) do { \
    __builtin_amdgcn_global_load_lds((AS1 void*)(Ap + (long)((h) * 64) * lda + (long)(kt) * 64), \
        (AS3 void*)(Ash + (d) * 16384 + (h) * 8192 + sdst), 16, 0, 0); \
    __builtin_amdgcn_global_load_lds((AS1 void*)(Ap + (long)((h) * 64 + 128) * lda + (long)(kt) * 64), \
        (AS3 void*)(Ash + (d) * 16384 + (h) * 8192 + 4096 + sdst), 16, 0, 0); \
} while (0)

#define STAGE_B(d, h, kt) do { \
    __builtin_amdgcn_global_load_lds((AS1 void*)(Bp0 + (long)((h) * 32) * ldb + (long)(kt) * 64), \
        (AS3 void*)(Bsh + (d) * 16384 + (h) * 8192 + sdst), 16, 0, 0); \
    __builtin_amdgcn_global_load_lds((AS1 void*)(Bp1 + (long)((h) * 32) * ldb + (long)(kt) * 64), \
        (AS3 void*)(Bsh + (d) * 16384 + (h) * 8192 + 4096 + sdst), 16, 0, 0); \
} while (0)

#define LDA_FRAGS(d, mh) do { \
    _Pragma("unroll") for (int mi_ = 0; mi_ < 4; mi_++) { \
        const _Float16* p_ = &Ash[(d) * 16384 + (mh) * 8192 + (arow + mi_ * 16) * 64]; \
        aF[mi_][0] = *(const half8*)&p_[kq0]; \
        aF[mi_][1] = *(const half8*)&p_[kq1]; \
    } \
} while (0)

#define LDB_FRAGS(d, nh) do { \
    _Pragma("unroll") for (int ni_ = 0; ni_ < 2; ni_++) { \
        const _Float16* p_ = &Bsh[(d) * 16384 + (nh) * 8192 + (brow + ni_ * 16) * 64]; \
        bF[nh][ni_][0] = *(const half8*)&p_[kq0]; \
        bF[nh][ni_][1] = *(const half8*)&p_[kq1]; \
    } \
} while (0)

#define MFMA16(mh, nh) do { \
    __builtin_amdgcn_s_setprio(1); \
    _Pragma("unroll") for (int mi_ = 0; mi_ < 4; mi_++) \
    _Pragma("unroll") for (int ni_ = 0; ni_ < 2; ni_++) { \
        acc[(mh) * 4 + mi_][(nh) * 2 + ni_] = __builtin_amdgcn_mfma_f32_16x16x32_f16( \
            aF[mi_][0], bF[nh][ni_][0], acc[(mh) * 4 + mi_][(nh) * 2 + ni_], 0, 0, 0); \
        acc[(mh) * 4 + mi_][(nh) * 2 + ni_] = __builtin_amdgcn_mfma_f32_16x16x32_f16( \
            aF[mi_][1], bF[nh][ni_][1], acc[(mh) * 4 + mi_][(nh) * 2 + ni_], 0, 0, 0); \
    } \
    __builtin_amdgcn_s_setprio(0); \
} while (0)

// barrier + compiler-only memory fence (no emitted instructions)
#define BAR() do { \
    asm volatile("" ::: "memory"); \
    __builtin_amdgcn_s_barrier(); \
    asm volatile("" ::: "memory"); \
} while (0)

template <int MODE>
__global__ __launch_bounds__(512, 2) void gemm256_kernel(
    const _Float16* __restrict__ A, const _Float16* __restrict__ Bt,
    void* __restrict__ Cv, const float* __restrict__ bias,
    const float* __restrict__ bias2,
    int nx, int ny, int K, int lda, int ldb, int ldc,
    long aBatch, long bBatch, long cBatch, float scale)
{
    __shared__ _Float16 smem[65536];   // 128 KiB
    _Float16* Ash = smem;
    _Float16* Bsh = smem + 32768;

    const int tid = threadIdx.x;
    const int wave = tid >> 6, lane = tid & 63;
    const int quad = lane >> 4, lr = lane & 15;
    const int wm = wave >> 2, wn = wave & 3;

    // XCD-aware swizzle (grid % 8 == 0 for all our launches)
    const int P = gridDim.x >> 3;
    const int g = (blockIdx.x & 7) * P + (blockIdx.x >> 3);
    const int pplane = nx * ny;
    const int z = g / pplane;
    const int rr = g - z * pplane;
    const int by = rr / nx;
    const int bx = rr - by * nx;
    const int m0 = by * 256, n0 = bx * 256;

    const _Float16* Ab = A + (long)z * aBatch;
    const _Float16* Bb = Bt + (long)z * bBatch;

    // ---- staging geometry: thread -> (local row sr, swizzled 16B chunk) ----
    const int sr0 = tid >> 3;                   // 0..63 (load 0); load 1 adds 64
    const int sc0 = (tid & 7) ^ (sr0 & 7);      // pre-swizzled global chunk
    const _Float16* Ap = Ab + (long)(m0 + sr0) * lda + sc0 * 8;
    const int bc0 = (sr0 & 31) + ((sr0 >> 5) << 6);          // B col, load 0, h=0
    const int bc1 = (sr0 & 31) + (((sr0 >> 5) + 2) << 6);    // B col, load 1, h=0
    const _Float16* Bp0 = Bb + (long)(n0 + bc0) * ldb + sc0 * 8;
    const _Float16* Bp1 = Bb + (long)(n0 + bc1) * ldb + sc0 * 8;
    const int sdst = tid * 8;                   // LDS elem offset (linear dest)

    // ---- fragment-read geometry (k-chunk XOR'd back) ----
    const int kq0 = (quad * 8) ^ ((lr & 7) << 3);
    const int kq1 = (32 + quad * 8) ^ ((lr & 7) << 3);
    const int arow = wm * 64 + lr;              // + mi*16 = A local row
    const int brow = wn * 32 + lr;              // + ni*16 = B local row

    half8 aF[4][2];        // [mi][ks], reloaded per mh
    half8 bF[2][2][2];     // [nh][ni][ks], held across the whole tile
    floatx4 acc[8][4] = {};
    const int NT = K >> 6;

    // ---- prologue: tile0 {A0,A1,B0,B1} + tile1 {A0,B0} = 12 loads/thread ----
    STAGE_A(0, 0, 0); STAGE_A(0, 1, 0); STAGE_B(0, 0, 0); STAGE_B(0, 1, 0);
    if (NT > 1) {
        STAGE_A(1, 0, 1); STAGE_B(1, 0, 1);
        asm volatile("s_waitcnt vmcnt(4)" ::: "memory");   // tile0's 8 loads landed
    } else {
        asm volatile("s_waitcnt vmcnt(0)" ::: "memory");
    }
    BAR();

    for (int t = 0; t < NT; t++) {
        const int d = t & 1, dn = d ^ 1;
        // phase 0: quadrant (mh=0, nh=0); stage (t+1).A1 -> other buf
        LDA_FRAGS(d, 0); LDB_FRAGS(d, 0);
        if (t + 1 < NT) STAGE_A(dn, 1, t + 1);
        BAR();
        MFMA16(0, 0);
        BAR();
        // phase 1: (0,1); stage (t+1).B1 -> other buf
        LDB_FRAGS(d, 1);
        if (t + 1 < NT) STAGE_B(dn, 1, t + 1);
        BAR();
        MFMA16(0, 1);
        BAR();
        // phase 2: (1,0); stage (t+2).A0 -> THIS buf (A-h0 dead since p0)
        LDA_FRAGS(d, 1);
        if (t + 2 < NT) STAGE_A(d, 0, t + 2);
        BAR();
        MFMA16(1, 0);
        BAR();
        // phase 3: (1,1); stage (t+2).B0 -> THIS buf (B-h0 dead since p0)
        if (t + 2 < NT) STAGE_B(d, 0, t + 2);
        BAR();
        MFMA16(1, 1);
        // tile boundary folded into phase-3 close: after the wait, all 4
        // halves of t+1 are resident; t+2's {A0,B0} stay in flight.
        if (t + 1 < NT) {
            if (t + 2 < NT) asm volatile("s_waitcnt vmcnt(4)" ::: "memory");
            else            asm volatile("s_waitcnt vmcnt(0)" ::: "memory");
        }
        BAR();
    }

    // ---- epilogue ----  C/D frag: m = quad*4 + r, n = lane&15
    if constexpr (MODE == 0) {
        _Float16* C = (_Float16*)Cv + (long)z * cBatch;
        const float* bz = (z == 0 || !bias2) ? bias : bias2;
#pragma unroll
        for (int ni = 0; ni < 4; ni++) {
            const int n = n0 + wn * 64 + ni * 16 + lr;
            const float bv_ = bz ? bz[n] : 0.0f;
#pragma unroll
            for (int mi = 0; mi < 8; mi++) {
                const int mb = m0 + wm * 128 + mi * 16 + quad * 4;
#pragma unroll
                for (int r = 0; r < 4; r++)
                    C[(long)(mb + r) * ldc + n] = (_Float16)((acc[mi][ni][r] + bv_) * scale);
            }
        }
    } else {
        float* C = (float*)Cv + (long)z * cBatch;
#pragma unroll
        for (int ni = 0; ni < 4; ni++) {
            const int n = n0 + wn * 64 + ni * 16 + lr;
#pragma unroll
            for (int mi = 0; mi < 8; mi++) {
                const int mb = m0 + wm * 128 + mi * 16 + quad * 4;
#pragma unroll
                for (int r = 0; r < 4; r++)
                    C[(long)(mb + r) * ldc + n] = acc[mi][ni][r] * scale;
            }
        }
    }
}

#undef STAGE_A
#undef STAGE_B
#undef LDA_FRAGS
#undef LDB_FRAGS
#undef MFMA16
#undef BAR

// ---------------------------------------------------------------------------
// row softmax, in place, fp16. One wave per row of 2048. block=256 -> 4 rows.
// ---------------------------------------------------------------------------
__global__ __launch_bounds__(256) void softmax_kernel(_Float16* __restrict__ buf)
{
    const int lane = threadIdx.x & 63;
    const long row = (long)blockIdx.x * 4 + (threadIdx.x >> 6);
    _Float16* p = buf + row * 2048;

    float f[32];
#pragma unroll
    for (int j = 0; j < 4; j++) {
        half8 v = *(const half8*)&p[lane * 8 + j * 512];
#pragma unroll
        for (int e = 0; e < 8; e++) f[j * 8 + e] = (float)v[e];
    }
    float m = -1e30f;
#pragma unroll
    for (int i = 0; i < 32; i++) m = fmaxf(m, f[i]);
#pragma unroll
    for (int off = 32; off; off >>= 1) m = fmaxf(m, __shfl_xor(m, off, 64));
    float s = 0.0f;
#pragma unroll
    for (int i = 0; i < 32; i++) { f[i] = __expf(f[i] - m); s += f[i]; }
#pragma unroll
    for (int off = 32; off; off >>= 1) s += __shfl_xor(s, off, 64);
    const float inv = 1.0f / s;
#pragma unroll
    for (int j = 0; j < 4; j++) {
        half8 v;
#pragma unroll
        for (int e = 0; e < 8; e++) v[e] = (_Float16)(f[j * 8 + e] * inv);
        *(half8*)&p[lane * 8 + j * 512] = v;
    }
}

// ---------------------------------------------------------------------------
// B=8, S=2048, D=1024.  Workspace layout (bytes):
//   Q   fp16 [16384][1024]            @ 0          (33,554,432)
//   Kb  fp16 [16384][1024]            @ 33,554,432 (33,554,432)   (contig w/ Q)
//   Vt  fp16 [8][1024][2048]          @ 67,108,864 (33,554,432)
//   Sc  fp16 [8][2048][2048]          @ 100,663,296 (67,108,864)  (xb aliased)
//   Wt  fp16 [3][1024][1024]          @ 167,772,160 (6,291,456)
// total 174,063,616
// ---------------------------------------------------------------------------
extern "C" void kernel_launch(void* const* d_in, const int* in_sizes, int n_in,
                              void* d_out, int out_size, void* d_ws, size_t ws_size,
                              hipStream_t stream)
{
    const float* x  = (const float*)d_in[0];
    const float* Wq = (const float*)d_in[1];
    const float* bq = (const float*)d_in[2];
    const float* Wk = (const float*)d_in[3];
    const float* bk = (const float*)d_in[4];
    const float* Wv = (const float*)d_in[5];
    const float* bv = (const float*)d_in[6];

    if (ws_size < 174063616u) return;  // cannot run

    char* ws = (char*)d_ws;
    _Float16* Q  = (_Float16*)(ws + 0);
    _Float16* Vt = (_Float16*)(ws + 67108864);
    _Float16* Sc = (_Float16*)(ws + 100663296);
    _Float16* Wt = (_Float16*)(ws + 167772160);
    _Float16* xb = Sc;  // aliased: xb dead before Sc is written
    _Float16* Kb = Q + 16777216;
    float* out = (float*)d_out;

    wtrans_kernel<<<dim3(16, 16, 3), 256, 0, stream>>>(Wq, Wk, Wv, Wt);
    f32_to_f16_kernel<<<2048, 256, 0, stream>>>(x, xb, 16777216);

    // Q and K projections fused via z: M=16384, N=1024, K=1024 -> 512 blocks
    gemm256_kernel<0><<<512, 512, 0, stream>>>(
        xb, Wt, Q, bq, bk, 4, 64, 1024, 1024, 1024, 1024,
        0, 1048576, 16777216, 1.0f);
    // V projection -> Vt [b][d][t] (old 128^2 MODE-1 kernel), 1024 blocks
    gemm128_kernel<1><<<1024, 256, 0, stream>>>(
        xb, Wt + 2097152, Vt, bv, nullptr, 8, 128, 1024, 1024, 1024, 2048,
        0, 0, 2097152, 1.0f);

    // scores = Q K^T / 32 : per-batch M=N=2048, K=1024 -> 512 blocks
    gemm256_kernel<0><<<512, 512, 0, stream>>>(
        Q, Kb, Sc, nullptr, nullptr, 8, 8, 1024, 1024, 1024, 2048,
        2097152, 2097152, 4194304, 0.03125f);

    softmax_kernel<<<4096, 256, 0, stream>>>(Sc);

    // out = P V : per-batch M=2048, N=1024, K=2048 -> 256 blocks
    gemm256_kernel<2><<<256, 512, 0, stream>>>(
        Sc, Vt, out, nullptr, nullptr, 4, 8, 2048, 2048, 2048, 1024,
        4194304, 2097152, 2097152, 1.0f);
}

// Round 6
// 434.338 us; speedup vs baseline: 1.0661x; 1.0253x over previous
//
#include <hip/hip_runtime.h>

typedef _Float16 half8 __attribute__((ext_vector_type(8)));
typedef float floatx4 __attribute__((ext_vector_type(4)));

#define AS1 __attribute__((address_space(1)))
#define AS3 __attribute__((address_space(3)))

// ---------------------------------------------------------------------------
// W transpose + fp32->fp16: W [1024][1024] (k,n) -> Wt [1024][1024] (n,k)
// grid (16,16,3), block 256. 64x64 tiles through LDS.
// ---------------------------------------------------------------------------
__global__ __launch_bounds__(256) void wtrans_kernel(
    const float* __restrict__ W0, const float* __restrict__ W1,
    const float* __restrict__ W2, _Float16* __restrict__ Wt)
{
    __shared__ _Float16 t[64 * 72];
    const float* W = (blockIdx.z == 0) ? W0 : (blockIdx.z == 1) ? W1 : W2;
    _Float16* O = Wt + (long)blockIdx.z * 1048576;
    const int tid = threadIdx.x;
    const int kb = blockIdx.y * 64, nb = blockIdx.x * 64;
#pragma unroll
    for (int i = 0; i < 4; i++) {
        int r = (tid >> 4) + i * 16;
        int c = (tid & 15) * 4;
        floatx4 w = *(const floatx4*)&W[(long)(kb + r) * 1024 + nb + c];
#pragma unroll
        for (int j = 0; j < 4; j++) t[(c + j) * 72 + r] = (_Float16)w[j];
    }
    __syncthreads();
    const int c = tid >> 2, rch = (tid & 3) * 16;
    half8 v0 = *(const half8*)&t[c * 72 + rch];
    half8 v1 = *(const half8*)&t[c * 72 + rch + 8];
    _Float16* o = &O[(long)(nb + c) * 1024 + kb + rch];
    *(half8*)o = v0;
    *(half8*)(o + 8) = v1;
}

// ---------------------------------------------------------------------------
// fp32 -> fp16 cast, 8 elems/thread, grid-stride
// ---------------------------------------------------------------------------
__global__ __launch_bounds__(256) void f32_to_f16_kernel(
    const float* __restrict__ in, _Float16* __restrict__ out, int n)
{
    for (long i = ((long)blockIdx.x * 256 + threadIdx.x) * 8; i < n;
         i += (long)gridDim.x * 256 * 8) {
        floatx4 a = *(const floatx4*)&in[i];
        floatx4 b = *(const floatx4*)&in[i + 4];
        half8 h;
#pragma unroll
        for (int e = 0; e < 4; e++) { h[e] = (_Float16)a[e]; h[e + 4] = (_Float16)b[e]; }
        *(half8*)&out[i] = h;
    }
}

// ---------------------------------------------------------------------------
// Old m97-style 128x128 GEMM — kept ONLY for MODE 1 (V-proj with transposed
// fp16 output through LDS).
// ---------------------------------------------------------------------------
template <int MODE>
__global__ __launch_bounds__(256) void gemm128_kernel(
    const _Float16* __restrict__ A, const _Float16* __restrict__ Bt,
    void* __restrict__ Cv, const float* __restrict__ bias,
    const float* __restrict__ bias2,
    int nx, int ny,
    int K, int lda, int ldb, int ldc,
    long aBatch, long bBatch, long cBatch, float scale)
{
    constexpr int SMEM_ELEMS = (MODE == 1) ? 17408 : 16384;
    __shared__ _Float16 smem[SMEM_ELEMS];
    _Float16* Ash = smem;
    _Float16* Bsh = smem + 8192;

    const int tid = threadIdx.x;
    const int wave = tid >> 6, lane = tid & 63;
    const int quad = lane >> 4, lr = lane & 15;
    const int wm = wave & 1, wn = wave >> 1;

    const int P = gridDim.x >> 3;
    const int g = (blockIdx.x & 7) * P + (blockIdx.x >> 3);
    const int pplane = nx * ny;
    const int z = g / pplane;
    const int rr = g - z * pplane;
    const int by = rr / nx;
    const int bx = rr - by * nx;
    const int m0 = by * 128, n0 = bx * 128;

    const _Float16* Ab = A + (long)z * aBatch;
    const _Float16* Bb = Bt + (long)z * bBatch;

    const int srow = tid >> 2;
    const int scol = (tid & 3) * 8;
    const long ag0 = (long)(m0 + srow) * lda + scol;
    const long bg0 = (long)(n0 + srow) * ldb + scol;
    const int sdst = tid * 8;

    floatx4 acc[4][4] = {};

    for (int k0 = 0; k0 < K; k0 += 64) {
#pragma unroll
        for (int s = 0; s < 2; s++) {
            const int kk = k0 + s * 32;
            const int so = s * 4096;
            __builtin_amdgcn_global_load_lds(
                (AS1 void*)(Ab + ag0 + kk), (AS3 void*)(Ash + so + sdst), 16, 0, 0);
            __builtin_amdgcn_global_load_lds(
                (AS1 void*)(Ab + ag0 + (long)64 * lda + kk), (AS3 void*)(Ash + so + sdst + 2048), 16, 0, 0);
            __builtin_amdgcn_global_load_lds(
                (AS1 void*)(Bb + bg0 + kk), (AS3 void*)(Bsh + so + sdst), 16, 0, 0);
            __builtin_amdgcn_global_load_lds(
                (AS1 void*)(Bb + bg0 + (long)64 * ldb + kk), (AS3 void*)(Bsh + so + sdst + 2048), 16, 0, 0);
        }
        __syncthreads();

#pragma unroll
        for (int s = 0; s < 2; s++) {
            const int so = s * 4096;
            half8 aF[4], bF[4];
#pragma unroll
            for (int i = 0; i < 4; i++) {
                aF[i] = *(const half8*)&Ash[so + (wm * 64 + i * 16 + lr) * 32 + quad * 8];
                bF[i] = *(const half8*)&Bsh[so + (wn * 64 + i * 16 + lr) * 32 + quad * 8];
            }
#pragma unroll
            for (int mi = 0; mi < 4; mi++)
#pragma unroll
                for (int ni = 0; ni < 4; ni++)
                    acc[mi][ni] = __builtin_amdgcn_mfma_f32_16x16x32_f16(
                        aF[mi], bF[ni], acc[mi][ni], 0, 0, 0);
        }
        __syncthreads();
    }

    if constexpr (MODE == 0) {
        _Float16* C = (_Float16*)Cv + (long)z * cBatch;
        const float* bz = (z == 0 || !bias2) ? bias : bias2;
#pragma unroll
        for (int ni = 0; ni < 4; ni++) {
            const int n = n0 + wn * 64 + ni * 16 + lr;
            const float bv_ = bz ? bz[n] : 0.0f;
#pragma unroll
            for (int mi = 0; mi < 4; mi++) {
                const int mb = m0 + wm * 64 + mi * 16 + quad * 4;
#pragma unroll
                for (int r = 0; r < 4; r++)
                    C[(long)(mb + r) * ldc + n] = (_Float16)((acc[mi][ni][r] + bv_) * scale);
            }
        }
    } else if constexpr (MODE == 1) {
        _Float16* ctile = smem;
#pragma unroll
        for (int ni = 0; ni < 4; ni++) {
            const int nl = wn * 64 + ni * 16 + lr;
            const float bv_ = bias ? bias[n0 + nl] : 0.0f;
#pragma unroll
            for (int mi = 0; mi < 4; mi++) {
                const int ml = wm * 64 + mi * 16 + quad * 4;
#pragma unroll
                for (int r = 0; r < 4; r++)
                    ctile[nl * 136 + ml + r] = (_Float16)((acc[mi][ni][r] + bv_) * scale);
            }
        }
        __syncthreads();
        _Float16* C = (_Float16*)Cv + (long)(m0 >> 11) * cBatch;
        const int t0 = m0 & 2047;
#pragma unroll
        for (int p = 0; p < 8; p++) {
            const int row = p * 16 + (tid >> 4);
            const int seg = (tid & 15) * 8;
            half8 v = *(const half8*)&ctile[row * 136 + seg];
            *(half8*)&C[(long)(n0 + row) * ldc + t0 + seg] = v;
        }
    } else {
        float* C = (float*)Cv + (long)z * cBatch;
#pragma unroll
        for (int ni = 0; ni < 4; ni++) {
            const int n = n0 + wn * 64 + ni * 16 + lr;
#pragma unroll
            for (int mi = 0; mi < 4; mi++) {
                const int mb = m0 + wm * 64 + mi * 16 + quad * 4;
#pragma unroll
                for (int r = 0; r < 4; r++)
                    C[(long)(mb + r) * ldc + n] = acc[mi][ni][r] * scale;
            }
        }
    }
}

// ---------------------------------------------------------------------------
// 256x256 8-phase GEMM, PIPELINED fragment reads — race-fixed (round 5,
// resubmitted after infra failure; byte-identical).
//   C[m][n] = sum_k A[m][k] * Bt[n][k]   (both fp16 row-major)
// 512 threads = 8 waves (2M x 4N), per-wave 128x64 output, BK=64.
// LDS 128 KiB, XOR-swizzled (0 bank conflicts, verified).
//
// Pipelined reads: each quadrant's ds_reads issue AFTER the previous MFMA
// cluster so they drain on the LDS pipe under the MFMA burst. Quadrant
// order (0,0)->(0,1)->(1,1)->(1,0) swaps one operand half per phase.
//
// vmcnt DISCIPLINE (the round-4 bug): vmcnt is PER-WAVE; a fragment read of
// data staged by OTHER waves is only safe after {their vmcnt covering that
// load} + {a barrier}. Issue order per thread per tile:
//   [t-1 ph2] A0(t+1) | [t-1 ph3] B0(t+1) | [ph0] A1(t+1) | [ph1] B1(t+1)
//   | [ph2] A0(t+2) | [ph3] B0(t+2)
// - end-ph2: vmcnt(6) (newest 6 = A1,B1(t+1),A0(t+2)) => A0,B0(t+1) landed;
//   end-ph2 BAR + ph3 pre-MFMA BAR transfer before the ph3-tail reads.
// - boundary: vmcnt(4) (newest 4 = A0,B0(t+2)) => A1,B1(t+1) landed;
//   end-ph3 BAR transfers before next tile's ph0/ph1 reads.
// - prologue: vmcnt(4) then BAR **then** tile-0 fragment reads.
// Both waits target loads issued >=2 phases earlier -> non-blocking.
// MODE 0: fp16 out row-major, (+bias per z)*scale.  MODE 2: fp32 out.
// ---------------------------------------------------------------------------
#define STAGE_A(d, h, kt) do { \
    __builtin_amdgcn_global_load_lds((AS1 void*)(Ap + (long)((h) * 64) * lda + (long)(kt) * 64), \
        (AS3 void*)(Ash + (d) * 16384 + (h) * 8192 + sdst), 16, 0, 0); \
    __builtin_amdgcn_global_load_lds((AS1 void*)(Ap + (long)((h) * 64 + 128) * lda + (long)(kt) * 64), \
        (AS3 void*)(Ash + (d) * 16384 + (h) * 8192 + 4096 + sdst), 16, 0, 0); \
} while (0)

#define STAGE_B(d, h, kt) do { \
    __builtin_amdgcn_global_load_lds((AS1 void*)(Bp0 + (long)((h) * 32) * ldb + (long)(kt) * 64), \
        (AS3 void*)(Bsh + (d) * 16384 + (h) * 8192 + sdst), 16, 0, 0); \
    __builtin_amdgcn_global_load_lds((AS1 void*)(Bp1 + (long)((h) * 32) * ldb + (long)(kt) * 64), \
        (AS3 void*)(Bsh + (d) * 16384 + (h) * 8192 + 4096 + sdst), 16, 0, 0); \
} while (0)

#define LDA_FRAGS(d, mh) do { \
    _Pragma("unroll") for (int mi_ = 0; mi_ < 4; mi_++) { \
        const _Float16* p_ = &Ash[(d) * 16384 + (mh) * 8192 + (arow + mi_ * 16) * 64]; \
        aF[mi_][0] = *(const half8*)&p_[kq0]; \
        aF[mi_][1] = *(const half8*)&p_[kq1]; \
    } \
} while (0)

#define LDB_FRAGS(d, nh) do { \
    _Pragma("unroll") for (int ni_ = 0; ni_ < 2; ni_++) { \
        const _Float16* p_ = &Bsh[(d) * 16384 + (nh) * 8192 + (brow + ni_ * 16) * 64]; \
        bF[nh][ni_][0] = *(const half8*)&p_[kq0]; \
        bF[nh][ni_][1] = *(const half8*)&p_[kq1]; \
    } \
} while (0)

#define MFMA16(mh, nh) do { \
    __builtin_amdgcn_s_setprio(1); \
    _Pragma("unroll") for (int mi_ = 0; mi_ < 4; mi_++) \
    _Pragma("unroll") for (int ni_ = 0; ni_ < 2; ni_++) { \
        acc[(mh) * 4 + mi_][(nh) * 2 + ni_] = __builtin_amdgcn_mfma_f32_16x16x32_f16( \
            aF[mi_][0], bF[nh][ni_][0], acc[(mh) * 4 + mi_][(nh) * 2 + ni_], 0, 0, 0); \
        acc[(mh) * 4 + mi_][(nh) * 2 + ni_] = __builtin_amdgcn_mfma_f32_16x16x32_f16( \
            aF[mi_][1], bF[nh][ni_][1], acc[(mh) * 4 + mi_][(nh) * 2 + ni_], 0, 0, 0); \
    } \
    __builtin_amdgcn_s_setprio(0); \
} while (0)

// barrier + compiler-only memory fence (no emitted instructions)
#define BAR() do { \
    asm volatile("" ::: "memory"); \
    __builtin_amdgcn_s_barrier(); \
    asm volatile("" ::: "memory"); \
} while (0)

template <int MODE>
__global__ __launch_bounds__(512, 2) void gemm256_kernel(
    const _Float16* __restrict__ A, const _Float16* __restrict__ Bt,
    void* __restrict__ Cv, const float* __restrict__ bias,
    const float* __restrict__ bias2,
    int nx, int ny, int K, int lda, int ldb, int ldc,
    long aBatch, long bBatch, long cBatch, float scale)
{
    __shared__ _Float16 smem[65536];   // 128 KiB
    _Float16* Ash = smem;
    _Float16* Bsh = smem + 32768;

    const int tid = threadIdx.x;
    const int wave = tid >> 6, lane = tid & 63;
    const int quad = lane >> 4, lr = lane & 15;
    const int wm = wave >> 2, wn = wave & 3;

    // XCD-aware swizzle (grid % 8 == 0 for all our launches)
    const int P = gridDim.x >> 3;
    const int g = (blockIdx.x & 7) * P + (blockIdx.x >> 3);
    const int pplane = nx * ny;
    const int z = g / pplane;
    const int rr = g - z * pplane;
    const int by = rr / nx;
    const int bx = rr - by * nx;
    const int m0 = by * 256, n0 = bx * 256;

    const _Float16* Ab = A + (long)z * aBatch;
    const _Float16* Bb = Bt + (long)z * bBatch;

    // ---- staging geometry: thread -> (local row sr, swizzled 16B chunk) ----
    const int sr0 = tid >> 3;                   // 0..63 (load 0); load 1 adds 64
    const int sc0 = (tid & 7) ^ (sr0 & 7);      // pre-swizzled global chunk
    const _Float16* Ap = Ab + (long)(m0 + sr0) * lda + sc0 * 8;
    const int bc0 = (sr0 & 31) + ((sr0 >> 5) << 6);          // B col, load 0, h=0
    const int bc1 = (sr0 & 31) + (((sr0 >> 5) + 2) << 6);    // B col, load 1, h=0
    const _Float16* Bp0 = Bb + (long)(n0 + bc0) * ldb + sc0 * 8;
    const _Float16* Bp1 = Bb + (long)(n0 + bc1) * ldb + sc0 * 8;
    const int sdst = tid * 8;                   // LDS elem offset (linear dest)

    // ---- fragment-read geometry (k-chunk XOR'd back) ----
    const int kq0 = (quad * 8) ^ ((lr & 7) << 3);
    const int kq1 = (32 + quad * 8) ^ ((lr & 7) << 3);
    const int arow = wm * 64 + lr;              // + mi*16 = A local row
    const int brow = wn * 32 + lr;              // + ni*16 = B local row

    half8 aF[4][2];        // [mi][ks], current A-half
    half8 bF[2][2][2];     // [nh][ni][ks], both B halves live across the tile
    floatx4 acc[8][4] = {};
    const int NT = K >> 6;

    // ---- prologue: tile0 {A0,A1,B0,B1} + tile1 {A0,B0} staged ----
    STAGE_A(0, 0, 0); STAGE_A(0, 1, 0); STAGE_B(0, 0, 0); STAGE_B(0, 1, 0);
    if (NT > 1) {
        STAGE_A(1, 0, 1); STAGE_B(1, 0, 1);
        asm volatile("s_waitcnt vmcnt(4)" ::: "memory");   // tile0's 8 loads landed
    } else {
        asm volatile("s_waitcnt vmcnt(0)" ::: "memory");
    }
    BAR();                 // transfers every wave's drain BEFORE anyone reads
    LDA_FRAGS(0, 0);       // tile-0 ph0 fragments, now safe
    LDB_FRAGS(0, 0);

    for (int t = 0; t < NT; t++) {
        const int d = t & 1, dn = d ^ 1;
        // ph0: bF1 <- B-h1(d) (drains under MFMA); MFMA(0,0) uses aF=A0,bF0
        LDB_FRAGS(d, 1);
        if (t + 1 < NT) STAGE_A(dn, 1, t + 1);
        BAR();
        MFMA16(0, 0);
        BAR();
        // ph1: MFMA(0,1) uses aF=A0,bF1; then aF <- A-h1(d) (WAR pins after)
        if (t + 1 < NT) STAGE_B(dn, 1, t + 1);
        BAR();
        MFMA16(0, 1);
        LDA_FRAGS(d, 1);
        BAR();
        // ph2: MFMA(1,1) uses aF=A1,bF1; end-ph2 vmcnt => A0,B0(t+1) landed
        if (t + 2 < NT) STAGE_A(d, 0, t + 2);
        BAR();
        MFMA16(1, 1);
        if (t + 1 < NT) {
            if (t + 2 < NT) asm volatile("s_waitcnt vmcnt(6)" ::: "memory");
            else            asm volatile("s_waitcnt vmcnt(4)" ::: "memory");
        }
        BAR();
        // ph3: MFMA(1,0) uses aF=A1,bF0; tail reads of A0,B0(t+1) are now
        // two barriers downstream of every wave's covering vmcnt -> safe.
        if (t + 2 < NT) STAGE_B(d, 0, t + 2);
        BAR();
        MFMA16(1, 0);
        if (t + 1 < NT) {
            LDA_FRAGS(dn, 0);
            LDB_FRAGS(dn, 0);
            // boundary: A1,B1(t+1) landed (newest 4 = A0,B0(t+2))
            if (t + 2 < NT) asm volatile("s_waitcnt vmcnt(4)" ::: "memory");
            else            asm volatile("s_waitcnt vmcnt(0)" ::: "memory");
        }
        BAR();
    }

    // ---- epilogue ----  C/D frag: m = quad*4 + r, n = lane&15
    if constexpr (MODE == 0) {
        _Float16* C = (_Float16*)Cv + (long)z * cBatch;
        const float* bz = (z == 0 || !bias2) ? bias : bias2;
#pragma unroll
        for (int ni = 0; ni < 4; ni++) {
            const int n = n0 + wn * 64 + ni * 16 + lr;
            const float bv_ = bz ? bz[n] : 0.0f;
#pragma unroll
            for (int mi = 0; mi < 8; mi++) {
                const int mb = m0 + wm * 128 + mi * 16 + quad * 4;
#pragma unroll
                for (int r = 0; r < 4; r++)
                    C[(long)(mb + r) * ldc + n] = (_Float16)((acc[mi][ni][r] + bv_) * scale);
            }
        }
    } else {
        float* C = (float*)Cv + (long)z * cBatch;
#pragma unroll
        for (int ni = 0; ni < 4; ni++) {
            const int n = n0 + wn * 64 + ni * 16 + lr;
#pragma unroll
            for (int mi = 0; mi < 8; mi++) {
                const int mb = m0 + wm * 128 + mi * 16 + quad * 4;
#pragma unroll
                for (int r = 0; r < 4; r++)
                    C[(long)(mb + r) * ldc + n] = acc[mi][ni][r] * scale;
            }
        }
    }
}

#undef STAGE_A
#undef STAGE_B
#undef LDA_FRAGS
#undef LDB_FRAGS
#undef MFMA16
#undef BAR

// ---------------------------------------------------------------------------
// row softmax, in place, fp16. One wave per row of 2048. block=256 -> 4 rows.
// ---------------------------------------------------------------------------
__global__ __launch_bounds__(256) void softmax_kernel(_Float16* __restrict__ buf)
{
    const int lane = threadIdx.x & 63;
    const long row = (long)blockIdx.x * 4 + (threadIdx.x >> 6);
    _Float16* p = buf + row * 2048;

    float f[32];
#pragma unroll
    for (int j = 0; j < 4; j++) {
        half8 v = *(const half8*)&p[lane * 8 + j * 512];
#pragma unroll
        for (int e = 0; e < 8; e++) f[j * 8 + e] = (float)v[e];
    }
    float m = -1e30f;
#pragma unroll
    for (int i = 0; i < 32; i++) m = fmaxf(m, f[i]);
#pragma unroll
    for (int off = 32; off; off >>= 1) m = fmaxf(m, __shfl_xor(m, off, 64));
    float s = 0.0f;
#pragma unroll
    for (int i = 0; i < 32; i++) { f[i] = __expf(f[i] - m); s += f[i]; }
#pragma unroll
    for (int off = 32; off; off >>= 1) s += __shfl_xor(s, off, 64);
    const float inv = 1.0f / s;
#pragma unroll
    for (int j = 0; j < 4; j++) {
        half8 v;
#pragma unroll
        for (int e = 0; e < 8; e++) v[e] = (_Float16)(f[j * 8 + e] * inv);
        *(half8*)&p[lane * 8 + j * 512] = v;
    }
}

// ---------------------------------------------------------------------------
// B=8, S=2048, D=1024.  Workspace layout (bytes):
//   Q   fp16 [16384][1024]            @ 0          (33,554,432)
//   Kb  fp16 [16384][1024]            @ 33,554,432 (33,554,432)   (contig w/ Q)
//   Vt  fp16 [8][1024][2048]          @ 67,108,864 (33,554,432)
//   Sc  fp16 [8][2048][2048]          @ 100,663,296 (67,108,864)  (xb aliased)
//   Wt  fp16 [3][1024][1024]          @ 167,772,160 (6,291,456)
// total 174,063,616
// ---------------------------------------------------------------------------
extern "C" void kernel_launch(void* const* d_in, const int* in_sizes, int n_in,
                              void* d_out, int out_size, void* d_ws, size_t ws_size,
                              hipStream_t stream)
{
    const float* x  = (const float*)d_in[0];
    const float* Wq = (const float*)d_in[1];
    const float* bq = (const float*)d_in[2];
    const float* Wk = (const float*)d_in[3];
    const float* bk = (const float*)d_in[4];
    const float* Wv = (const float*)d_in[5];
    const float* bv = (const float*)d_in[6];

    if (ws_size < 174063616u) return;  // cannot run

    char* ws = (char*)d_ws;
    _Float16* Q  = (_Float16*)(ws + 0);
    _Float16* Vt = (_Float16*)(ws + 67108864);
    _Float16* Sc = (_Float16*)(ws + 100663296);
    _Float16* Wt = (_Float16*)(ws + 167772160);
    _Float16* xb = Sc;  // aliased: xb dead before Sc is written
    _Float16* Kb = Q + 16777216;
    float* out = (float*)d_out;

    wtrans_kernel<<<dim3(16, 16, 3), 256, 0, stream>>>(Wq, Wk, Wv, Wt);
    f32_to_f16_kernel<<<2048, 256, 0, stream>>>(x, xb, 16777216);

    // Q and K projections fused via z: M=16384, N=1024, K=1024 -> 512 blocks
    gemm256_kernel<0><<<512, 512, 0, stream>>>(
        xb, Wt, Q, bq, bk, 4, 64, 1024, 1024, 1024, 1024,
        0, 1048576, 16777216, 1.0f);
    // V projection -> Vt [b][d][t] (old 128^2 MODE-1 kernel), 1024 blocks
    gemm128_kernel<1><<<1024, 256, 0, stream>>>(
        xb, Wt + 2097152, Vt, bv, nullptr, 8, 128, 1024, 1024, 1024, 2048,
        0, 0, 2097152, 1.0f);

    // scores = Q K^T / 32 : per-batch M=N=2048, K=1024 -> 512 blocks
    gemm256_kernel<0><<<512, 512, 0, stream>>>(
        Q, Kb, Sc, nullptr, nullptr, 8, 8, 1024, 1024, 1024, 2048,
        2097152, 2097152, 4194304, 0.03125f);

    softmax_kernel<<<4096, 256, 0, stream>>>(Sc);

    // out = P V : per-batch M=2048, N=1024, K=2048 -> 256 blocks
    gemm256_kernel<2><<<256, 512, 0, stream>>>(
        Sc, Vt, out, nullptr, nullptr, 4, 8, 2048, 2048, 2048, 1024,
        4194304, 2097152, 2097152, 1.0f);
}

// Round 8
// 423.461 us; speedup vs baseline: 1.0934x; 1.0257x over previous
//
#include <hip/hip_runtime.h>

typedef _Float16 half8 __attribute__((ext_vector_type(8)));
typedef float floatx4 __attribute__((ext_vector_type(4)));

#define AS1 __attribute__((address_space(1)))
#define AS3 __attribute__((address_space(3)))

// ---------------------------------------------------------------------------
// W transpose + fp32->fp16: W [1024][1024] (k,n) -> Wt [1024][1024] (n,k)
// ---------------------------------------------------------------------------
__global__ __launch_bounds__(256) void wtrans_kernel(
    const float* __restrict__ W0, const float* __restrict__ W1,
    const float* __restrict__ W2, _Float16* __restrict__ Wt)
{
    __shared__ _Float16 t[64 * 72];
    const float* W = (blockIdx.z == 0) ? W0 : (blockIdx.z == 1) ? W1 : W2;
    _Float16* O = Wt + (long)blockIdx.z * 1048576;
    const int tid = threadIdx.x;
    const int kb = blockIdx.y * 64, nb = blockIdx.x * 64;
#pragma unroll
    for (int i = 0; i < 4; i++) {
        int r = (tid >> 4) + i * 16;
        int c = (tid & 15) * 4;
        floatx4 w = *(const floatx4*)&W[(long)(kb + r) * 1024 + nb + c];
#pragma unroll
        for (int j = 0; j < 4; j++) t[(c + j) * 72 + r] = (_Float16)w[j];
    }
    __syncthreads();
    const int c = tid >> 2, rch = (tid & 3) * 16;
    half8 v0 = *(const half8*)&t[c * 72 + rch];
    half8 v1 = *(const half8*)&t[c * 72 + rch + 8];
    _Float16* o = &O[(long)(nb + c) * 1024 + kb + rch];
    *(half8*)o = v0;
    *(half8*)(o + 8) = v1;
}

// ---------------------------------------------------------------------------
// fp32 -> fp16 cast, 8 elems/thread, grid-stride
// ---------------------------------------------------------------------------
__global__ __launch_bounds__(256) void f32_to_f16_kernel(
    const float* __restrict__ in, _Float16* __restrict__ out, int n)
{
    for (long i = ((long)blockIdx.x * 256 + threadIdx.x) * 8; i < n;
         i += (long)gridDim.x * 256 * 8) {
        floatx4 a = *(const floatx4*)&in[i];
        floatx4 b = *(const floatx4*)&in[i + 4];
        half8 h;
#pragma unroll
        for (int e = 0; e < 4; e++) { h[e] = (_Float16)a[e]; h[e + 4] = (_Float16)b[e]; }
        *(half8*)&out[i] = h;
    }
}

// ---------------------------------------------------------------------------
// Old m97-style 128x128 GEMM — kept ONLY for MODE 1 (V-proj, transposed out).
// ---------------------------------------------------------------------------
template <int MODE>
__global__ __launch_bounds__(256) void gemm128_kernel(
    const _Float16* __restrict__ A, const _Float16* __restrict__ Bt,
    void* __restrict__ Cv, const float* __restrict__ bias,
    const float* __restrict__ bias2,
    int nx, int ny,
    int K, int lda, int ldb, int ldc,
    long aBatch, long bBatch, long cBatch, float scale)
{
    constexpr int SMEM_ELEMS = (MODE == 1) ? 17408 : 16384;
    __shared__ _Float16 smem[SMEM_ELEMS];
    _Float16* Ash = smem;
    _Float16* Bsh = smem + 8192;

    const int tid = threadIdx.x;
    const int wave = tid >> 6, lane = tid & 63;
    const int quad = lane >> 4, lr = lane & 15;
    const int wm = wave & 1, wn = wave >> 1;

    const int P = gridDim.x >> 3;
    const int g = (blockIdx.x & 7) * P + (blockIdx.x >> 3);
    const int pplane = nx * ny;
    const int z = g / pplane;
    const int rr = g - z * pplane;
    const int by = rr / nx;
    const int bx = rr - by * nx;
    const int m0 = by * 128, n0 = bx * 128;

    const _Float16* Ab = A + (long)z * aBatch;
    const _Float16* Bb = Bt + (long)z * bBatch;

    const int srow = tid >> 2;
    const int scol = (tid & 3) * 8;
    const long ag0 = (long)(m0 + srow) * lda + scol;
    const long bg0 = (long)(n0 + srow) * ldb + scol;
    const int sdst = tid * 8;

    floatx4 acc[4][4] = {};

    for (int k0 = 0; k0 < K; k0 += 64) {
#pragma unroll
        for (int s = 0; s < 2; s++) {
            const int kk = k0 + s * 32;
            const int so = s * 4096;
            __builtin_amdgcn_global_load_lds(
                (AS1 void*)(Ab + ag0 + kk), (AS3 void*)(Ash + so + sdst), 16, 0, 0);
            __builtin_amdgcn_global_load_lds(
                (AS1 void*)(Ab + ag0 + (long)64 * lda + kk), (AS3 void*)(Ash + so + sdst + 2048), 16, 0, 0);
            __builtin_amdgcn_global_load_lds(
                (AS1 void*)(Bb + bg0 + kk), (AS3 void*)(Bsh + so + sdst), 16, 0, 0);
            __builtin_amdgcn_global_load_lds(
                (AS1 void*)(Bb + bg0 + (long)64 * ldb + kk), (AS3 void*)(Bsh + so + sdst + 2048), 16, 0, 0);
        }
        __syncthreads();

#pragma unroll
        for (int s = 0; s < 2; s++) {
            const int so = s * 4096;
            half8 aF[4], bF[4];
#pragma unroll
            for (int i = 0; i < 4; i++) {
                aF[i] = *(const half8*)&Ash[so + (wm * 64 + i * 16 + lr) * 32 + quad * 8];
                bF[i] = *(const half8*)&Bsh[so + (wn * 64 + i * 16 + lr) * 32 + quad * 8];
            }
#pragma unroll
            for (int mi = 0; mi < 4; mi++)
#pragma unroll
                for (int ni = 0; ni < 4; ni++)
                    acc[mi][ni] = __builtin_amdgcn_mfma_f32_16x16x32_f16(
                        aF[mi], bF[ni], acc[mi][ni], 0, 0, 0);
        }
        __syncthreads();
    }

    if constexpr (MODE == 0) {
        _Float16* C = (_Float16*)Cv + (long)z * cBatch;
        const float* bz = (z == 0 || !bias2) ? bias : bias2;
#pragma unroll
        for (int ni = 0; ni < 4; ni++) {
            const int n = n0 + wn * 64 + ni * 16 + lr;
            const float bv_ = bz ? bz[n] : 0.0f;
#pragma unroll
            for (int mi = 0; mi < 4; mi++) {
                const int mb = m0 + wm * 64 + mi * 16 + quad * 4;
#pragma unroll
                for (int r = 0; r < 4; r++)
                    C[(long)(mb + r) * ldc + n] = (_Float16)((acc[mi][ni][r] + bv_) * scale);
            }
        }
    } else if constexpr (MODE == 1) {
        _Float16* ctile = smem;
#pragma unroll
        for (int ni = 0; ni < 4; ni++) {
            const int nl = wn * 64 + ni * 16 + lr;
            const float bv_ = bias ? bias[n0 + nl] : 0.0f;
#pragma unroll
            for (int mi = 0; mi < 4; mi++) {
                const int ml = wm * 64 + mi * 16 + quad * 4;
#pragma unroll
                for (int r = 0; r < 4; r++)
                    ctile[nl * 136 + ml + r] = (_Float16)((acc[mi][ni][r] + bv_) * scale);
            }
        }
        __syncthreads();
        _Float16* C = (_Float16*)Cv + (long)(m0 >> 11) * cBatch;
        const int t0 = m0 & 2047;
#pragma unroll
        for (int p = 0; p < 8; p++) {
            const int row = p * 16 + (tid >> 4);
            const int seg = (tid & 15) * 8;
            half8 v = *(const half8*)&ctile[row * 136 + seg];
            *(half8*)&C[(long)(n0 + row) * ldc + t0 + seg] = v;
        }
    } else {
        float* C = (float*)Cv + (long)z * cBatch;
#pragma unroll
        for (int ni = 0; ni < 4; ni++) {
            const int n = n0 + wn * 64 + ni * 16 + lr;
#pragma unroll
            for (int mi = 0; mi < 4; mi++) {
                const int mb = m0 + wm * 64 + mi * 16 + quad * 4;
#pragma unroll
                for (int r = 0; r < 4; r++)
                    C[(long)(mb + r) * ldc + n] = acc[mi][ni][r] * scale;
            }
        }
    }
}

// ---------------------------------------------------------------------------
// 256x256 GEMM, one-barrier-per-phase schedule, PEELED TAIL (round 8).
//   C[m][n] = sum_k A[m][k] * Bt[n][k]   (fp16 row-major)
// 512 thr = 8 waves (2Mx4N), per-wave 128x64, BK=64, LDS 128K XOR-swizzled.
//
// Phase = {reads | stage | vmcnt(N)+barrier | MFMA}. ONE barrier/phase ->
// wave skew overlaps LDS reads with other waves' MFMA (T3 mechanism; gives
// setprio a role-split, T5). Iter = 2 K-tiles (even->buf0 p0-3, odd->buf1
// p4-7), quadrant rotation (0,0)(0,1)(1,1)(1,0); B-frags of both halves
// held so p3/p7 have no reads.
//
// Stage slots: p0:(b1,B1,t+1) p1:(b1,A1,t+1) p2:(b0,A0,t+2) p3:(b0,B0,t+2)
//              p4:(b0,B1,t+2) p5:(b0,A1,t+2) p6:(b1,A0,t+3) p7:(b1,B0,t+3)
// MAIN LOOP runs i < NI-1 with stages UNCONDITIONAL -> the vmcnt(8)
// invariant ("all but newest 4 half-stages landed") holds at every barrier;
// each read's staging is >=4 slots older than its covering wait. WAR: every
// stage targets a region last read >=2 barriers upstream (verified).
//
// ROUND-7 BUG (fixed): the guarded last iteration staged only 2 slots, so
// vmcnt(8)'s newest-8 window still contained the stages its reads needed.
// FIX: peel the last iteration; drain with descending counted waits
// 8,8,8,4,2,0 (each wait's target issued >=2 phases earlier), final two
// MFMA phases barrier-free. Verified for NI=1 and NI>=2.
// MODE 0: fp16 out (+bias per z)*scale.  MODE 2: fp32 out.
// ---------------------------------------------------------------------------
#define STAGE_A(d, h, kt) do { \
    __builtin_amdgcn_global_load_lds((AS1 void*)(Ap + (long)((h) * 64) * lda + (long)(kt) * 64), \
        (AS3 void*)(Ash + (d) * 16384 + (h) * 8192 + sdst), 16, 0, 0); \
    __builtin_amdgcn_global_load_lds((AS1 void*)(Ap + (long)((h) * 64 + 128) * lda + (long)(kt) * 64), \
        (AS3 void*)(Ash + (d) * 16384 + (h) * 8192 + 4096 + sdst), 16, 0, 0); \
} while (0)

#define STAGE_B(d, h, kt) do { \
    __builtin_amdgcn_global_load_lds((AS1 void*)(Bp0 + (long)((h) * 32) * ldb + (long)(kt) * 64), \
        (AS3 void*)(Bsh + (d) * 16384 + (h) * 8192 + sdst), 16, 0, 0); \
    __builtin_amdgcn_global_load_lds((AS1 void*)(Bp1 + (long)((h) * 32) * ldb + (long)(kt) * 64), \
        (AS3 void*)(Bsh + (d) * 16384 + (h) * 8192 + 4096 + sdst), 16, 0, 0); \
} while (0)

#define LDA_FRAGS(d, mh) do { \
    _Pragma("unroll") for (int mi_ = 0; mi_ < 4; mi_++) { \
        const _Float16* p_ = &Ash[(d) * 16384 + (mh) * 8192 + (arow + mi_ * 16) * 64]; \
        aF[mi_][0] = *(const half8*)&p_[kq0]; \
        aF[mi_][1] = *(const half8*)&p_[kq1]; \
    } \
} while (0)

#define LDB_FRAGS(d, nh) do { \
    _Pragma("unroll") for (int ni_ = 0; ni_ < 2; ni_++) { \
        const _Float16* p_ = &Bsh[(d) * 16384 + (nh) * 8192 + (brow + ni_ * 16) * 64]; \
        bF[nh][ni_][0] = *(const half8*)&p_[kq0]; \
        bF[nh][ni_][1] = *(const half8*)&p_[kq1]; \
    } \
} while (0)

#define MFMA16(mh, nh) do { \
    __builtin_amdgcn_s_setprio(1); \
    _Pragma("unroll") for (int mi_ = 0; mi_ < 4; mi_++) \
    _Pragma("unroll") for (int ni_ = 0; ni_ < 2; ni_++) { \
        acc[(mh) * 4 + mi_][(nh) * 2 + ni_] = __builtin_amdgcn_mfma_f32_16x16x32_f16( \
            aF[mi_][0], bF[nh][ni_][0], acc[(mh) * 4 + mi_][(nh) * 2 + ni_], 0, 0, 0); \
        acc[(mh) * 4 + mi_][(nh) * 2 + ni_] = __builtin_amdgcn_mfma_f32_16x16x32_f16( \
            aF[mi_][1], bF[nh][ni_][1], acc[(mh) * 4 + mi_][(nh) * 2 + ni_], 0, 0, 0); \
    } \
    __builtin_amdgcn_s_setprio(0); \
} while (0)

// counted wait + barrier + compiler-only memory fences (one barrier/phase)
#define VMBAR(n) do { \
    asm volatile("s_waitcnt vmcnt(" #n ")" ::: "memory"); \
    __builtin_amdgcn_s_barrier(); \
    asm volatile("" ::: "memory"); \
} while (0)

template <int MODE>
__global__ __launch_bounds__(512, 2) void gemm256_kernel(
    const _Float16* __restrict__ A, const _Float16* __restrict__ Bt,
    void* __restrict__ Cv, const float* __restrict__ bias,
    const float* __restrict__ bias2,
    int nx, int ny, int K, int lda, int ldb, int ldc,
    long aBatch, long bBatch, long cBatch, float scale)
{
    __shared__ _Float16 smem[65536];   // 128 KiB
    _Float16* Ash = smem;
    _Float16* Bsh = smem + 32768;

    const int tid = threadIdx.x;
    const int wave = tid >> 6, lane = tid & 63;
    const int quad = lane >> 4, lr = lane & 15;
    const int wm = wave >> 2, wn = wave & 3;

    // XCD-aware swizzle (grid % 8 == 0 for all our launches)
    const int P = gridDim.x >> 3;
    const int g = (blockIdx.x & 7) * P + (blockIdx.x >> 3);
    const int pplane = nx * ny;
    const int z = g / pplane;
    const int rr = g - z * pplane;
    const int by = rr / nx;
    const int bx = rr - by * nx;
    const int m0 = by * 256, n0 = bx * 256;

    const _Float16* Ab = A + (long)z * aBatch;
    const _Float16* Bb = Bt + (long)z * bBatch;

    // ---- staging geometry: thread -> (local row sr, swizzled 16B chunk) ----
    const int sr0 = tid >> 3;                   // 0..63 (load 0); load 1 adds 64
    const int sc0 = (tid & 7) ^ (sr0 & 7);      // pre-swizzled global chunk
    const _Float16* Ap = Ab + (long)(m0 + sr0) * lda + sc0 * 8;
    const int bc0 = (sr0 & 31) + ((sr0 >> 5) << 6);          // B col, load 0, h=0
    const int bc1 = (sr0 & 31) + (((sr0 >> 5) + 2) << 6);    // B col, load 1, h=0
    const _Float16* Bp0 = Bb + (long)(n0 + bc0) * ldb + sc0 * 8;
    const _Float16* Bp1 = Bb + (long)(n0 + bc1) * ldb + sc0 * 8;
    const int sdst = tid * 8;                   // LDS elem offset (linear dest)

    // ---- fragment-read geometry (k-chunk XOR'd back) ----
    const int kq0 = (quad * 8) ^ ((lr & 7) << 3);
    const int kq1 = (32 + quad * 8) ^ ((lr & 7) << 3);
    const int arow = wm * 64 + lr;              // + mi*16 = A local row
    const int brow = wn * 32 + lr;              // + ni*16 = B local row

    half8 aF[4][2];        // [mi][ks], current A-half
    half8 bF[2][2][2];     // [nh][ni][ks], both B halves live per tile
    floatx4 acc[8][4] = {};
    const int NT = K >> 6;       // even (16 or 32)
    const int NI = NT >> 1;

    // ---- prologue: t0 {A0,B0,B1,A1} + t1 {A0,B0} = 6 half-stages ----
    STAGE_A(0, 0, 0); STAGE_B(0, 0, 0); STAGE_B(0, 1, 0); STAGE_A(0, 1, 0);
    STAGE_A(1, 0, 1); STAGE_B(1, 0, 1);
    asm volatile("s_waitcnt vmcnt(4)" ::: "memory");   // t0's 4 halves landed
    __builtin_amdgcn_s_barrier();
    asm volatile("" ::: "memory");

    // ---- main loop: NI-1 full iterations, stages unconditional ----
    for (int i = 0; i < NI - 1; ++i) {
        const int t1 = 2 * i + 1, t2 = 2 * i + 2, t3 = 2 * i + 3;  // all < NT
        // p0: reads A(b0,h0)+B(b0,h0); stage odd.B1
        LDA_FRAGS(0, 0); LDB_FRAGS(0, 0);
        STAGE_B(1, 1, t1);
        VMBAR(8);
        MFMA16(0, 0);
        // p1: reads B(b0,h1); stage odd.A1
        LDB_FRAGS(0, 1);
        STAGE_A(1, 1, t1);
        VMBAR(8);
        MFMA16(0, 1);
        // p2: reads A(b0,h1); stage even'.A0
        LDA_FRAGS(0, 1);
        STAGE_A(0, 0, t2);
        VMBAR(8);
        MFMA16(1, 1);
        // p3: (no reads, bF0 held); stage even'.B0
        STAGE_B(0, 0, t2);
        VMBAR(8);
        MFMA16(1, 0);
        // p4: reads A(b1,h0)+B(b1,h0); stage even'.B1
        LDA_FRAGS(1, 0); LDB_FRAGS(1, 0);
        STAGE_B(0, 1, t2);
        VMBAR(8);
        MFMA16(0, 0);
        // p5: reads B(b1,h1); stage even'.A1
        LDB_FRAGS(1, 1);
        STAGE_A(0, 1, t2);
        VMBAR(8);
        MFMA16(0, 1);
        // p6: reads A(b1,h1); stage odd'.A0
        LDA_FRAGS(1, 1);
        STAGE_A(1, 0, t3);
        VMBAR(8);
        MFMA16(1, 1);
        // p7: (no reads); stage odd'.B0
        STAGE_B(1, 0, t3);
        VMBAR(8);
        MFMA16(1, 0);
    }

    // ---- peeled last iteration: tiles NT-2 (b0), NT-1 (b1); drain 8,8,8,4,2,0
    {
        const int tl = NT - 1;
        // p0: reads A0,B0(b0) [staged prev p2,p3; covered by prev p7 VMBAR(8)]
        LDA_FRAGS(0, 0); LDB_FRAGS(0, 0);
        STAGE_B(1, 1, tl);
        VMBAR(8);
        MFMA16(0, 0);
        // p1: reads B1(b0) [prev p4; covered]
        LDB_FRAGS(0, 1);
        STAGE_A(1, 1, tl);
        VMBAR(8);
        MFMA16(0, 1);
        // p2: reads A1(b0) [prev p5; covered]
        LDA_FRAGS(0, 1);
        VMBAR(8);
        MFMA16(1, 1);
        // p3: no reads; drain so A0,B0(b1) [prev p6,p7] are landed for p4
        VMBAR(4);
        MFMA16(1, 0);
        // p4: reads A0,B0(b1); drain so B1(b1) [peel p0] lands for p5
        LDA_FRAGS(1, 0); LDB_FRAGS(1, 0);
        VMBAR(2);
        MFMA16(0, 0);
        // p5: reads B1(b1); drain so A1(b1) [peel p1] lands for p6
        LDB_FRAGS(1, 1);
        VMBAR(0);
        MFMA16(0, 1);
        // p6/p7: reads A1(b1) (all staging landed); no more barriers needed
        LDA_FRAGS(1, 1);
        MFMA16(1, 1);
        MFMA16(1, 0);
    }

    // ---- epilogue ----  C/D frag: m = quad*4 + r, n = lane&15
    if constexpr (MODE == 0) {
        _Float16* C = (_Float16*)Cv + (long)z * cBatch;
        const float* bz = (z == 0 || !bias2) ? bias : bias2;
#pragma unroll
        for (int ni = 0; ni < 4; ni++) {
            const int n = n0 + wn * 64 + ni * 16 + lr;
            const float bv_ = bz ? bz[n] : 0.0f;
#pragma unroll
            for (int mi = 0; mi < 8; mi++) {
                const int mb = m0 + wm * 128 + mi * 16 + quad * 4;
#pragma unroll
                for (int r = 0; r < 4; r++)
                    C[(long)(mb + r) * ldc + n] = (_Float16)((acc[mi][ni][r] + bv_) * scale);
            }
        }
    } else {
        float* C = (float*)Cv + (long)z * cBatch;
#pragma unroll
        for (int ni = 0; ni < 4; ni++) {
            const int n = n0 + wn * 64 + ni * 16 + lr;
#pragma unroll
            for (int mi = 0; mi < 8; mi++) {
                const int mb = m0 + wm * 128 + mi * 16 + quad * 4;
#pragma unroll
                for (int r = 0; r < 4; r++)
                    C[(long)(mb + r) * ldc + n] = acc[mi][ni][r] * scale;
            }
        }
    }
}

#undef STAGE_A
#undef STAGE_B
#undef LDA_FRAGS
#undef LDB_FRAGS
#undef MFMA16
#undef VMBAR

// ---------------------------------------------------------------------------
// row softmax, in place, fp16. One wave per row of 2048. block=256 -> 4 rows.
// ---------------------------------------------------------------------------
__global__ __launch_bounds__(256) void softmax_kernel(_Float16* __restrict__ buf)
{
    const int lane = threadIdx.x & 63;
    const long row = (long)blockIdx.x * 4 + (threadIdx.x >> 6);
    _Float16* p = buf + row * 2048;

    float f[32];
#pragma unroll
    for (int j = 0; j < 4; j++) {
        half8 v = *(const half8*)&p[lane * 8 + j * 512];
#pragma unroll
        for (int e = 0; e < 8; e++) f[j * 8 + e] = (float)v[e];
    }
    float m = -1e30f;
#pragma unroll
    for (int i = 0; i < 32; i++) m = fmaxf(m, f[i]);
#pragma unroll
    for (int off = 32; off; off >>= 1) m = fmaxf(m, __shfl_xor(m, off, 64));
    float s = 0.0f;
#pragma unroll
    for (int i = 0; i < 32; i++) { f[i] = __expf(f[i] - m); s += f[i]; }
#pragma unroll
    for (int off = 32; off; off >>= 1) s += __shfl_xor(s, off, 64);
    const float inv = 1.0f / s;
#pragma unroll
    for (int j = 0; j < 4; j++) {
        half8 v;
#pragma unroll
        for (int e = 0; e < 8; e++) v[e] = (_Float16)(f[j * 8 + e] * inv);
        *(half8*)&p[lane * 8 + j * 512] = v;
    }
}

// ---------------------------------------------------------------------------
// B=8, S=2048, D=1024.  Workspace layout (bytes):
//   Q   fp16 [16384][1024]            @ 0          (33,554,432)
//   Kb  fp16 [16384][1024]            @ 33,554,432 (33,554,432)   (contig w/ Q)
//   Vt  fp16 [8][1024][2048]          @ 67,108,864 (33,554,432)
//   Sc  fp16 [8][2048][2048]          @ 100,663,296 (67,108,864)  (xb aliased)
//   Wt  fp16 [3][1024][1024]          @ 167,772,160 (6,291,456)
// total 174,063,616
// ---------------------------------------------------------------------------
extern "C" void kernel_launch(void* const* d_in, const int* in_sizes, int n_in,
                              void* d_out, int out_size, void* d_ws, size_t ws_size,
                              hipStream_t stream)
{
    const float* x  = (const float*)d_in[0];
    const float* Wq = (const float*)d_in[1];
    const float* bq = (const float*)d_in[2];
    const float* Wk = (const float*)d_in[3];
    const float* bk = (const float*)d_in[4];
    const float* Wv = (const float*)d_in[5];
    const float* bv = (const float*)d_in[6];

    if (ws_size < 174063616u) return;  // cannot run

    char* ws = (char*)d_ws;
    _Float16* Q  = (_Float16*)(ws + 0);
    _Float16* Vt = (_Float16*)(ws + 67108864);
    _Float16* Sc = (_Float16*)(ws + 100663296);
    _Float16* Wt = (_Float16*)(ws + 167772160);
    _Float16* xb = Sc;  // aliased: xb dead before Sc is written
    _Float16* Kb = Q + 16777216;
    float* out = (float*)d_out;

    wtrans_kernel<<<dim3(16, 16, 3), 256, 0, stream>>>(Wq, Wk, Wv, Wt);
    f32_to_f16_kernel<<<2048, 256, 0, stream>>>(x, xb, 16777216);

    // Q and K projections fused via z: M=16384, N=1024, K=1024 -> 512 blocks
    gemm256_kernel<0><<<512, 512, 0, stream>>>(
        xb, Wt, Q, bq, bk, 4, 64, 1024, 1024, 1024, 1024,
        0, 1048576, 16777216, 1.0f);
    // V projection -> Vt [b][d][t] (old 128^2 MODE-1 kernel), 1024 blocks
    gemm128_kernel<1><<<1024, 256, 0, stream>>>(
        xb, Wt + 2097152, Vt, bv, nullptr, 8, 128, 1024, 1024, 1024, 2048,
        0, 0, 2097152, 1.0f);

    // scores = Q K^T / 32 : per-batch M=N=2048, K=1024 -> 512 blocks
    gemm256_kernel<0><<<512, 512, 0, stream>>>(
        Q, Kb, Sc, nullptr, nullptr, 8, 8, 1024, 1024, 1024, 2048,
        2097152, 2097152, 4194304, 0.03125f);

    softmax_kernel<<<4096, 256, 0, stream>>>(Sc);

    // out = P V : per-batch M=2048, N=1024, K=2048 -> 256 blocks
    gemm256_kernel<2><<<256, 512, 0, stream>>>(
        Sc, Vt, out, nullptr, nullptr, 4, 8, 2048, 2048, 2048, 1024,
        4194304, 2097152, 2097152, 1.0f);
}